// Round 7
// baseline (381.881 us; speedup 1.0000x reference)
//
#include <hip/hip_runtime.h>
#include <hip/hip_bf16.h>
#include <cstdint>
#include <cstddef>

#define NUM_NODES 500000
#define DIM 128
#define BATCH 131072

typedef __attribute__((ext_vector_type(8))) short short8;
typedef __attribute__((ext_vector_type(4))) short short4_t;
typedef __attribute__((ext_vector_type(4))) float f32x4;

static __device__ __forceinline__ short f2bf(float f) {
    unsigned u = __builtin_bit_cast(unsigned, f);
    u += 0x7fffu + ((u >> 16) & 1u);   // round-to-nearest-even
    return (short)(u >> 16);
}
static __device__ __forceinline__ float bf2f(short s) {
    unsigned u = ((unsigned)(unsigned short)s) << 16;
    return __builtin_bit_cast(float, u);
}

// ---------------------------------------------------------------- init ----
__global__ void k_init(unsigned char* __restrict__ mask,
                       const float* __restrict__ Wih,
                       const float* __restrict__ Whh,
                       short* __restrict__ WbIH,
                       short* __restrict__ WbHH,
                       int do_mask) {
    int i = blockIdx.x * blockDim.x + threadIdx.x;
    if (do_mask && i < NUM_NODES) mask[i] = 0;
    if (i < 3 * DIM * DIM) {
        WbIH[i] = f2bf(Wih[i]);
        WbHH[i] = f2bf(Whh[i]);
    }
}

__global__ void k_scatter(unsigned char* __restrict__ mask, const int* __restrict__ idx) {
    int i = blockIdx.x * blockDim.x + threadIdx.x;
    if (i < BATCH) mask[idx[i]] = 1;
}

// ---------------------------------------------------------------- copy ----
// FROZEN from R5 (A/B isolation): 256 thr, no LDS, 16 thr/row, 32B/plane.
__global__ void __launch_bounds__(256)
k_copy(const float* __restrict__ hidden,
       const float* __restrict__ variance,
       const unsigned char* __restrict__ mask,   // null -> copy all
       float* __restrict__ out0,
       float* __restrict__ out1) {
    int gid = blockIdx.x * 256 + threadIdx.x;
    int row = gid >> 4;
    int c8  = gid & 15;
    if (mask && mask[row]) return;               // gru writes this row
    size_t off = (size_t)row * DIM + c8 * 8;
    f32x4 a0 = *(const f32x4*)(hidden + off);
    f32x4 a1 = *(const f32x4*)(hidden + off + 4);
    f32x4 b0 = *(const f32x4*)(variance + off);
    f32x4 b1 = *(const f32x4*)(variance + off + 4);
    *(f32x4*)(out0 + off)     = a0;
    *(f32x4*)(out0 + off + 4) = a1;
    *(f32x4*)(out1 + off)     = b0;
    *(f32x4*)(out1 + off + 4) = b1;
}

// ----------------------------------------------------------------- gru ----
// v7: 256 thr = 4 waves, 16 rows/block, 8192 blocks. Wave w owns output dims
// 32w..32w+31 (two 16-wide N-tiles). Gate-third loop OUTER so only acc[2][2]
// is live across the K loop (register diet -> occupancy). LDS 13KB.
__global__ void __launch_bounds__(256)
k_gru(const float* __restrict__ hidden,
      const float* __restrict__ variance,
      const int*   __restrict__ idx,
      const float* __restrict__ xg,       // new_repr
      const short* __restrict__ WbIH,     // [384][128] bf16 bits
      const short* __restrict__ WbHH,
      const float* __restrict__ b_ih,
      const float* __restrict__ b_hh,
      float* __restrict__ out0,
      float* __restrict__ out1) {
    __shared__ __align__(16) char smem[13056];
    short (*Xb)[136] = (short(*)[136])smem;             // bf16 x tile
    short (*Hb)[136] = (short(*)[136])(smem + 4352);    // bf16 h tile
    short (*Vb)[136] = (short(*)[136])(smem + 8704);    // bf16 variance tile
    short (*Hn)[136] = (short(*)[136])smem;             // bf16 h_new, OVERLAYS Xb

    const int t  = threadIdx.x;
    const int rb = blockIdx.x * 16;

    // ---- stage x, gathered h, gathered variance (bf16) ----
    #pragma unroll
    for (int jj = 0; jj < 2; ++jj) {
        int j = t + jj * 256;                           // 512 f32x4 chunks
        int row = j >> 5, c4 = j & 31;
        int node = idx[rb + row];
        f32x4 xv = *(const f32x4*)(xg + (size_t)(rb + row) * DIM + c4 * 4);
        f32x4 hv = *(const f32x4*)(hidden + (size_t)node * DIM + c4 * 4);
        f32x4 vv = *(const f32x4*)(variance + (size_t)node * DIM + c4 * 4);
        short4_t xs, hs, vs;
        xs.x = f2bf(xv.x); xs.y = f2bf(xv.y); xs.z = f2bf(xv.z); xs.w = f2bf(xv.w);
        hs.x = f2bf(hv.x); hs.y = f2bf(hv.y); hs.z = f2bf(hv.z); hs.w = f2bf(hv.w);
        vs.x = f2bf(vv.x); vs.y = f2bf(vv.y); vs.z = f2bf(vv.z); vs.w = f2bf(vv.w);
        *(short4_t*)&Xb[row][c4 * 4] = xs;
        *(short4_t*)&Hb[row][c4 * 4] = hs;
        *(short4_t*)&Vb[row][c4 * 4] = vs;
    }
    __syncthreads();

    const int w  = t >> 6;       // wave id 0..3 -> dims 32w..32w+31
    const int l  = t & 63;
    const int c  = l & 15;
    const int gq = l >> 4;

    // per-third results; th 0/1 pre-summed, th 2 kept split (r * gh_n)
    float s_r[2][4], s_z[2][4], gin[2][4], ghn[2][4];

    #pragma unroll
    for (int th = 0; th < 3; ++th) {
        f32x4 acc[2][2] = {};    // [n-tile][0=x@Wih 1=h@Whh] -- only 16 live regs
        #pragma unroll
        for (int ks = 0; ks < 4; ++ks) {
            const int k0 = ks * 32 + gq * 8;
            const short8 aX = *(const short8*)&Xb[c][k0];
            const short8 aH = *(const short8*)&Hb[c][k0];
            #pragma unroll
            for (int nt = 0; nt < 2; ++nt) {
                const int o = th * 128 + w * 32 + nt * 16 + c;   // W output row
                const short8 bi = *(const short8*)(WbIH + (size_t)o * DIM + k0);
                const short8 bh = *(const short8*)(WbHH + (size_t)o * DIM + k0);
                acc[nt][0] = __builtin_amdgcn_mfma_f32_16x16x32_bf16(aX, bi, acc[nt][0], 0, 0, 0);
                acc[nt][1] = __builtin_amdgcn_mfma_f32_16x16x32_bf16(aH, bh, acc[nt][1], 0, 0, 0);
            }
        }
        #pragma unroll
        for (int nt = 0; nt < 2; ++nt)
            #pragma unroll
            for (int r = 0; r < 4; ++r) {
                if (th == 0) s_r[nt][r] = acc[nt][0][r] + acc[nt][1][r];
                if (th == 1) s_z[nt][r] = acc[nt][0][r] + acc[nt][1][r];
                if (th == 2) { gin[nt][r] = acc[nt][0][r]; ghn[nt][r] = acc[nt][1][r]; }
            }
    }
    __syncthreads();   // all Xb reads done -> Hn overlay safe

    // ---- gate math; lane holds (m = gq*4 + r, d = 32w + 16nt + c) ----
    #pragma unroll
    for (int nt = 0; nt < 2; ++nt) {
        const int d = w * 32 + nt * 16 + c;
        const float bsr = b_ih[d]       + b_hh[d];
        const float bsz = b_ih[d + 128] + b_hh[d + 128];
        const float bin = b_ih[d + 256];
        const float bhn = b_hh[d + 256];
        #pragma unroll
        for (int r = 0; r < 4; ++r) {
            const int m = gq * 4 + r;
            float rg = 1.f / (1.f + __expf(-(s_r[nt][r] + bsr)));
            float zg = 1.f / (1.f + __expf(-(s_z[nt][r] + bsz)));
            float aa = (gin[nt][r] + bin) + rg * (ghn[nt][r] + bhn);
            float n  = 1.f - 2.f / (__expf(2.f * aa) + 1.f);   // tanh, inf-safe
            float h  = bf2f(Hb[m][d]);
            Hn[m][d] = f2bf((1.f - zg) * n + zg * h);
        }
    }
    __syncthreads();

    // ---- epilogue: pure LDS reads, coalesced f32x4 stores ----
    #pragma unroll
    for (int jj = 0; jj < 2; ++jj) {
        int j = t + jj * 256;
        int row = j >> 5, c4 = j & 31;
        int node = idx[rb + row];                  // L1-hot re-read
        size_t off = (size_t)node * DIM + c4 * 4;
        short4_t hns = *(short4_t*)&Hn[row][c4 * 4];
        short4_t hs  = *(short4_t*)&Hb[row][c4 * 4];
        short4_t vs  = *(short4_t*)&Vb[row][c4 * 4];
        f32x4 hn, var;
        hn.x = bf2f(hns.x); hn.y = bf2f(hns.y); hn.z = bf2f(hns.z); hn.w = bf2f(hns.w);
        float dx = hn.x - bf2f(hs.x), dy = hn.y - bf2f(hs.y);
        float dz = hn.z - bf2f(hs.z), dw = hn.w - bf2f(hs.w);
        var.x = 0.9f * bf2f(vs.x) + 0.1f * dx * dx;
        var.y = 0.9f * bf2f(vs.y) + 0.1f * dy * dy;
        var.z = 0.9f * bf2f(vs.z) + 0.1f * dz * dz;
        var.w = 0.9f * bf2f(vs.w) + 0.1f * dw * dw;
        *(f32x4*)(out0 + off) = hn;
        *(f32x4*)(out1 + off) = var;
    }
}

// -------------------------------------------------------------- launch ----
extern "C" void kernel_launch(void* const* d_in, const int* in_sizes, int n_in,
                              void* d_out, int out_size, void* d_ws, size_t ws_size,
                              hipStream_t stream) {
    const float* hidden   = (const float*)d_in[0];
    const float* variance = (const float*)d_in[1];
    const int*   idx      = (const int*)d_in[2];
    const float* x        = (const float*)d_in[3];
    const float* Wih      = (const float*)d_in[4];
    const float* Whh      = (const float*)d_in[5];
    const float* bih      = (const float*)d_in[6];
    const float* bhh      = (const float*)d_in[7];
    float* out0 = (float*)d_out;
    float* out1 = out0 + (size_t)NUM_NODES * DIM;

    const size_t maskBytes = (size_t)NUM_NODES;               // 1 byte per node
    const size_t wBytes    = (size_t)3 * DIM * DIM * 2;       // per matrix (bf16)
    const bool   have_mask = ws_size >= maskBytes + 16 + 2 * wBytes;

    unsigned char* mask = have_mask ? (unsigned char*)d_ws : nullptr;
    short* WbIH = have_mask ? (short*)((char*)d_ws + ((maskBytes + 15) & ~size_t(15)))
                            : (short*)d_ws;
    short* WbHH = WbIH + 3 * DIM * DIM;

    k_init<<<(NUM_NODES + 255) / 256, 256, 0, stream>>>(
        mask ? mask : (unsigned char*)d_ws, Wih, Whh, WbIH, WbHH, have_mask ? 1 : 0);

    if (have_mask)
        k_scatter<<<BATCH / 256, 256, 0, stream>>>(mask, idx);

    // copy non-updated rows (copy-all if no mask), then gru writes its rows
    k_copy<<<(NUM_NODES * 16) / 256, 256, 0, stream>>>(
        hidden, variance, mask, out0, out1);

    k_gru<<<BATCH / 16, 256, 0, stream>>>(hidden, variance, idx, x,
                                          WbIH, WbHH, bih, bhh, out0, out1);
}

// Round 8
// 293.604 us; speedup vs baseline: 1.3007x; 1.3007x over previous
//
#include <hip/hip_runtime.h>
#include <hip/hip_bf16.h>
#include <cstdint>
#include <cstddef>

#define NUM_NODES 500000
#define DIM 128
#define BATCH 131072

typedef __attribute__((ext_vector_type(8))) short short8;
typedef __attribute__((ext_vector_type(4))) short short4_t;
typedef __attribute__((ext_vector_type(4))) float f32x4;

static __device__ __forceinline__ short f2bf(float f) {
    unsigned u = __builtin_bit_cast(unsigned, f);
    u += 0x7fffu + ((u >> 16) & 1u);   // round-to-nearest-even
    return (short)(u >> 16);
}
static __device__ __forceinline__ float bf2f(short s) {
    unsigned u = ((unsigned)(unsigned short)s) << 16;
    return __builtin_bit_cast(float, u);
}

// ---------------------------------------------------------------- init ----
__global__ void k_init(unsigned char* __restrict__ mask,
                       const float* __restrict__ Wih,
                       const float* __restrict__ Whh,
                       short* __restrict__ WbIH,
                       short* __restrict__ WbHH,
                       int do_mask) {
    int i = blockIdx.x * blockDim.x + threadIdx.x;
    if (do_mask && i < NUM_NODES) mask[i] = 0;
    if (i < 3 * DIM * DIM) {
        WbIH[i] = f2bf(Wih[i]);
        WbHH[i] = f2bf(Whh[i]);
    }
}

__global__ void k_scatter(unsigned char* __restrict__ mask, const int* __restrict__ idx) {
    int i = blockIdx.x * blockDim.x + threadIdx.x;
    if (i < BATCH) mask[idx[i]] = 1;
}

// ----------------------------------------------------------------- gru ----
// v8: h_new ONLY. 512 thr = 8 waves, 32 rows/block, 4096 blocks.
// LDS 17.4KB (Xb+Hb bf16) -> 4 blocks/CU. One barrier. Direct f32 scatter
// of h_new (4 x 64B segments per store instr -- full lines covered in aggregate).
__global__ void __launch_bounds__(512)
k_gru(const float* __restrict__ hidden,
      const int*   __restrict__ idx,
      const float* __restrict__ xg,       // new_repr
      const short* __restrict__ WbIH,     // [384][128] bf16 bits
      const short* __restrict__ WbHH,
      const float* __restrict__ b_ih,
      const float* __restrict__ b_hh,
      float* __restrict__ out0) {
    __shared__ __align__(16) short Xb[32][136];
    __shared__ __align__(16) short Hb[32][136];

    const int t  = threadIdx.x;
    const int rb = blockIdx.x * 32;

    // ---- stage x + gathered h (bf16) ----
    #pragma unroll
    for (int jj = 0; jj < 2; ++jj) {
        int j = t + jj * 512;                           // 1024 f32x4 chunks
        int row = j >> 5, c4 = j & 31;
        int node = idx[rb + row];
        f32x4 xv = *(const f32x4*)(xg + (size_t)(rb + row) * DIM + c4 * 4);
        f32x4 hv = *(const f32x4*)(hidden + (size_t)node * DIM + c4 * 4);
        short4_t xs, hs;
        xs.x = f2bf(xv.x); xs.y = f2bf(xv.y); xs.z = f2bf(xv.z); xs.w = f2bf(xv.w);
        hs.x = f2bf(hv.x); hs.y = f2bf(hv.y); hs.z = f2bf(hv.z); hs.w = f2bf(hv.w);
        *(short4_t*)&Xb[row][c4 * 4] = xs;
        *(short4_t*)&Hb[row][c4 * 4] = hs;
    }
    __syncthreads();

    const int w  = t >> 6;       // wave id 0..7 -> output dims 16w..16w+15
    const int l  = t & 63;
    const int c  = l & 15;
    const int gq = l >> 4;

    f32x4 acc[2][3][2] = {};     // [m-tile][gate third][0=x@Wih 1=h@Whh]

    #pragma unroll
    for (int ks = 0; ks < 4; ++ks) {
        const int k0 = ks * 32 + gq * 8;
        short8 a[2][2];
        a[0][0] = *(const short8*)&Xb[c][k0];
        a[1][0] = *(const short8*)&Xb[16 + c][k0];
        a[0][1] = *(const short8*)&Hb[c][k0];
        a[1][1] = *(const short8*)&Hb[16 + c][k0];
        #pragma unroll
        for (int th = 0; th < 3; ++th) {
            const int o = w * 16 + th * 128 + c;        // gate output row of W
            const short8 bi = *(const short8*)(WbIH + (size_t)o * DIM + k0);
            const short8 bh = *(const short8*)(WbHH + (size_t)o * DIM + k0);
            #pragma unroll
            for (int mt = 0; mt < 2; ++mt) {
                acc[mt][th][0] = __builtin_amdgcn_mfma_f32_16x16x32_bf16(a[mt][0], bi, acc[mt][th][0], 0, 0, 0);
                acc[mt][th][1] = __builtin_amdgcn_mfma_f32_16x16x32_bf16(a[mt][1], bh, acc[mt][th][1], 0, 0, 0);
            }
        }
    }

    // ---- gate math + direct store; lane holds (m = mt*16+gq*4+r, d = 16w+c) ----
    const int d = w * 16 + c;
    const float bs_r = b_ih[d]       + b_hh[d];
    const float bs_z = b_ih[d + 128] + b_hh[d + 128];
    const float bi_n = b_ih[d + 256];
    const float bh_n = b_hh[d + 256];

    #pragma unroll
    for (int mt = 0; mt < 2; ++mt) {
        #pragma unroll
        for (int r = 0; r < 4; ++r) {
            const int m = mt * 16 + gq * 4 + r;
            float s_r  = acc[mt][0][0][r] + acc[mt][0][1][r] + bs_r;
            float s_z  = acc[mt][1][0][r] + acc[mt][1][1][r] + bs_z;
            float gi_n = acc[mt][2][0][r] + bi_n;
            float gh_n = acc[mt][2][1][r] + bh_n;
            float rg = 1.f / (1.f + __expf(-s_r));
            float zg = 1.f / (1.f + __expf(-s_z));
            float aa = gi_n + rg * gh_n;
            float n  = 1.f - 2.f / (__expf(2.f * aa) + 1.f);   // tanh, inf-safe
            float h  = bf2f(Hb[m][d]);
            float hn = (1.f - zg) * n + zg * h;
            int node = idx[rb + m];                    // L1-hot
            out0[(size_t)node * DIM + d] = hn;
        }
    }
}

// ------------------------------------------------------------- finish ----
// Pure streaming over ALL rows, zero LDS, 31250 blocks x 256.
// unmasked: copy both planes. masked: read back h_new (gru wrote out0),
// var = 0.9v + 0.1(hn - h)^2 with EXACT f32 h; write out1 only.
__global__ void __launch_bounds__(256)
k_fin(const float* __restrict__ hidden,
      const float* __restrict__ variance,
      const unsigned char* __restrict__ mask,
      float* __restrict__ out0,
      float* __restrict__ out1) {
    int gid = blockIdx.x * 256 + threadIdx.x;
    int row = gid >> 4;
    int c8  = gid & 15;
    size_t off = (size_t)row * DIM + c8 * 8;
    f32x4 h0 = *(const f32x4*)(hidden + off);
    f32x4 h1 = *(const f32x4*)(hidden + off + 4);
    f32x4 v0 = *(const f32x4*)(variance + off);
    f32x4 v1 = *(const f32x4*)(variance + off + 4);
    if (mask[row]) {
        f32x4 n0 = *(const f32x4*)(out0 + off);
        f32x4 n1 = *(const f32x4*)(out0 + off + 4);
        f32x4 w0, w1;
        float d;
        d = n0.x - h0.x; w0.x = 0.9f * v0.x + 0.1f * d * d;
        d = n0.y - h0.y; w0.y = 0.9f * v0.y + 0.1f * d * d;
        d = n0.z - h0.z; w0.z = 0.9f * v0.z + 0.1f * d * d;
        d = n0.w - h0.w; w0.w = 0.9f * v0.w + 0.1f * d * d;
        d = n1.x - h1.x; w1.x = 0.9f * v1.x + 0.1f * d * d;
        d = n1.y - h1.y; w1.y = 0.9f * v1.y + 0.1f * d * d;
        d = n1.z - h1.z; w1.z = 0.9f * v1.z + 0.1f * d * d;
        d = n1.w - h1.w; w1.w = 0.9f * v1.w + 0.1f * d * d;
        *(f32x4*)(out1 + off)     = w0;
        *(f32x4*)(out1 + off + 4) = w1;
    } else {
        *(f32x4*)(out0 + off)     = h0;
        *(f32x4*)(out0 + off + 4) = h1;
        *(f32x4*)(out1 + off)     = v0;
        *(f32x4*)(out1 + off + 4) = v1;
    }
}

// fallback var-fix when no mask space: over BATCH rows via idx
__global__ void __launch_bounds__(256)
k_varfix(const float* __restrict__ hidden,
         const float* __restrict__ variance,
         const int* __restrict__ idx,
         const float* __restrict__ out0,
         float* __restrict__ out1) {
    int gid = blockIdx.x * 256 + threadIdx.x;
    int i   = gid >> 4;
    int c8  = gid & 15;
    int node = idx[i];
    size_t off = (size_t)node * DIM + c8 * 8;
    f32x4 h0 = *(const f32x4*)(hidden + off);
    f32x4 h1 = *(const f32x4*)(hidden + off + 4);
    f32x4 v0 = *(const f32x4*)(variance + off);
    f32x4 v1 = *(const f32x4*)(variance + off + 4);
    f32x4 n0 = *(const f32x4*)(out0 + off);
    f32x4 n1 = *(const f32x4*)(out0 + off + 4);
    f32x4 w0, w1;
    float d;
    d = n0.x - h0.x; w0.x = 0.9f * v0.x + 0.1f * d * d;
    d = n0.y - h0.y; w0.y = 0.9f * v0.y + 0.1f * d * d;
    d = n0.z - h0.z; w0.z = 0.9f * v0.z + 0.1f * d * d;
    d = n0.w - h0.w; w0.w = 0.9f * v0.w + 0.1f * d * d;
    d = n1.x - h1.x; w1.x = 0.9f * v1.x + 0.1f * d * d;
    d = n1.y - h1.y; w1.y = 0.9f * v1.y + 0.1f * d * d;
    d = n1.z - h1.z; w1.z = 0.9f * v1.z + 0.1f * d * d;
    d = n1.w - h1.w; w1.w = 0.9f * v1.w + 0.1f * d * d;
    *(f32x4*)(out1 + off)     = w0;
    *(f32x4*)(out1 + off + 4) = w1;
}

// plain copy-all (fallback only)
__global__ void __launch_bounds__(256)
k_copyall(const float* __restrict__ hidden,
          const float* __restrict__ variance,
          float* __restrict__ out0,
          float* __restrict__ out1) {
    int gid = blockIdx.x * 256 + threadIdx.x;
    int row = gid >> 4;
    int c8  = gid & 15;
    size_t off = (size_t)row * DIM + c8 * 8;
    f32x4 a0 = *(const f32x4*)(hidden + off);
    f32x4 a1 = *(const f32x4*)(hidden + off + 4);
    f32x4 b0 = *(const f32x4*)(variance + off);
    f32x4 b1 = *(const f32x4*)(variance + off + 4);
    *(f32x4*)(out0 + off)     = a0;
    *(f32x4*)(out0 + off + 4) = a1;
    *(f32x4*)(out1 + off)     = b0;
    *(f32x4*)(out1 + off + 4) = b1;
}

// -------------------------------------------------------------- launch ----
extern "C" void kernel_launch(void* const* d_in, const int* in_sizes, int n_in,
                              void* d_out, int out_size, void* d_ws, size_t ws_size,
                              hipStream_t stream) {
    const float* hidden   = (const float*)d_in[0];
    const float* variance = (const float*)d_in[1];
    const int*   idx      = (const int*)d_in[2];
    const float* x        = (const float*)d_in[3];
    const float* Wih      = (const float*)d_in[4];
    const float* Whh      = (const float*)d_in[5];
    const float* bih      = (const float*)d_in[6];
    const float* bhh      = (const float*)d_in[7];
    float* out0 = (float*)d_out;
    float* out1 = out0 + (size_t)NUM_NODES * DIM;

    const size_t maskBytes = (size_t)NUM_NODES;               // 1 byte per node
    const size_t wBytes    = (size_t)3 * DIM * DIM * 2;       // per matrix (bf16)
    const bool   have_mask = ws_size >= maskBytes + 16 + 2 * wBytes;

    unsigned char* mask = have_mask ? (unsigned char*)d_ws : nullptr;
    short* WbIH = have_mask ? (short*)((char*)d_ws + ((maskBytes + 15) & ~size_t(15)))
                            : (short*)d_ws;
    short* WbHH = WbIH + 3 * DIM * DIM;

    k_init<<<(NUM_NODES + 255) / 256, 256, 0, stream>>>(
        mask ? mask : (unsigned char*)d_ws, Wih, Whh, WbIH, WbHH, have_mask ? 1 : 0);

    if (have_mask) {
        k_scatter<<<BATCH / 256, 256, 0, stream>>>(mask, idx);
        k_gru<<<BATCH / 32, 512, 0, stream>>>(hidden, idx, x,
                                              WbIH, WbHH, bih, bhh, out0);
        k_fin<<<(NUM_NODES * 16) / 256, 256, 0, stream>>>(
            hidden, variance, mask, out0, out1);
    } else {
        k_copyall<<<(NUM_NODES * 16) / 256, 256, 0, stream>>>(
            hidden, variance, out0, out1);
        k_gru<<<BATCH / 32, 512, 0, stream>>>(hidden, idx, x,
                                              WbIH, WbHH, bih, bhh, out0);
        k_varfix<<<(BATCH * 16) / 256, 256, 0, stream>>>(
            hidden, variance, idx, out0, out1);
    }
}